// Round 1
// baseline (34431.506 us; speedup 1.0000x reference)
//
#include <hip/hip_runtime.h>
#include <cstdint>
#include <cstddef>

// ---------- types ----------
typedef __attribute__((ext_vector_type(8))) short short8;   // 8 bf16 in 4 VGPRs
typedef __attribute__((ext_vector_type(4))) float f32x4;

#define B_ 64
#define T_ 512
#define I_ 256
#define H_ 1024
#define O_ 256

__device__ __forceinline__ unsigned short f32_to_bf16(float f) {
  unsigned int u = __float_as_uint(f);
  u += 0x7fffu + ((u >> 16) & 1u);           // RNE
  return (unsigned short)(u >> 16);
}
__device__ __forceinline__ float bf16_to_f32(unsigned short h) {
  return __uint_as_float(((unsigned int)h) << 16);
}

__device__ __forceinline__ void gload_lds16(const void* g, void* l) {
  __builtin_amdgcn_global_load_lds((const __attribute__((address_space(1))) void*)g,
                                   (__attribute__((address_space(3))) void*)l, 16, 0, 0);
}

// ---------- conversion kernels ----------
__global__ void cvt_f32_bf16(const float4* __restrict__ s, ushort4* __restrict__ d, int n4) {
  int i = blockIdx.x * blockDim.x + threadIdx.x;
  if (i >= n4) return;
  float4 v = s[i];
  ushort4 o;
  o.x = f32_to_bf16(v.x); o.y = f32_to_bf16(v.y);
  o.z = f32_to_bf16(v.z); o.w = f32_to_bf16(v.w);
  d[i] = o;
}

__global__ void bias_sum(const float* __restrict__ a, const float* __restrict__ b,
                         float* __restrict__ o, int n) {
  int i = blockIdx.x * blockDim.x + threadIdx.x;
  if (i < n) o[i] = a[i] + b[i];
}

// ---------- GEMM: C[M,N] = A[M,K] @ Bm[N,K]^T + bias, 128x128 tile (m97 structure) ----------
template<int OUT_F32>
__global__ __launch_bounds__(256) void gemm_bt(
    const unsigned short* __restrict__ A, const unsigned short* __restrict__ Bm,
    const float* __restrict__ bias, void* __restrict__ Cout, int N_, int K_)
{
  __shared__ unsigned short As[128*32];
  __shared__ unsigned short Bs[128*32];
  const int tid = threadIdx.x;
  const int l = tid & 63, w = tid >> 6;
  const int row0 = blockIdx.y * 128, col0 = blockIdx.x * 128;
  const int wr = w >> 1, wc = w & 1;          // 2x2 waves, each 64x64
  const int lrow = l & 15, lk8 = (l >> 4) * 8;

  f32x4 acc[4][4] = {};

  const int nkb = K_ >> 5;
  for (int kb = 0; kb < nkb; ++kb) {
    #pragma unroll
    for (int c = 0; c < 2; ++c) {
      const int off = w*2048 + c*1024 + l*16;   // byte offset within 8KB tile
      const int row = off >> 6, colb = off & 63;
      gload_lds16((const char*)A  + ((size_t)(row0+row)*K_ + kb*32)*2 + colb,
                  (char*)As + w*2048 + c*1024);
      gload_lds16((const char*)Bm + ((size_t)(col0+row)*K_ + kb*32)*2 + colb,
                  (char*)Bs + w*2048 + c*1024);
    }
    __syncthreads();
    short8 af[4], bfr[4];
    #pragma unroll
    for (int m=0;m<4;++m) af[m]  = *(const short8*)&As[(wr*64 + m*16 + lrow)*32 + lk8];
    #pragma unroll
    for (int n=0;n<4;++n) bfr[n] = *(const short8*)&Bs[(wc*64 + n*16 + lrow)*32 + lk8];
    #pragma unroll
    for (int m=0;m<4;++m)
      #pragma unroll
      for (int n=0;n<4;++n)
        acc[m][n] = __builtin_amdgcn_mfma_f32_16x16x32_bf16(af[m], bfr[n], acc[m][n], 0,0,0);
    __syncthreads();
  }

  #pragma unroll
  for (int n=0;n<4;++n) {
    const int col = col0 + wc*64 + n*16 + lrow;
    const float bv = bias[col];
    #pragma unroll
    for (int m=0;m<4;++m) {
      const int rowb = row0 + wr*64 + m*16 + (l>>4)*4;
      #pragma unroll
      for (int r=0;r<4;++r) {
        const float v = acc[m][n][r] + bv;
        if (OUT_F32) ((float*)Cout)[(size_t)(rowb+r)*N_ + col] = v;
        else ((unsigned short*)Cout)[(size_t)(rowb+r)*N_ + col] = f32_to_bf16(v);
      }
    }
  }
}

// ---------- group barrier (16 wgs per sample-group, device-scope) ----------
__device__ __forceinline__ void group_barrier(int* cnt, int expected) {
  __threadfence();                 // release all prior global writes (agent scope)
  __syncthreads();                 // whole wg done writing
  if (threadIdx.x == 0) {
    __hip_atomic_fetch_add(cnt, 1, __ATOMIC_RELEASE, __HIP_MEMORY_SCOPE_AGENT);
    while (__hip_atomic_load(cnt, __ATOMIC_ACQUIRE, __HIP_MEMORY_SCOPE_AGENT) < expected) {}
  }
  __syncthreads();
  __builtin_amdgcn_fence(__ATOMIC_ACQUIRE, "agent");
}

// ---------- RNN scan ----------
// 256 wgs: sg = wg&15 (4 samples), rg = wg>>4 (64 hidden rows). 4 waves, wave w
// owns 16 rows (one N-tile), Whh rows held in registers across all 512 steps.
// MODE 0: h buffer is H1[B*T][H] (reads t-1 row, writes t row).
// MODE 1: h buffer is ping-pong [2][B][H]; final state in slot (T-1)&1 = 1.
template<int MODE>
__global__ __launch_bounds__(256, 1) void rnn_scan(
    const unsigned short* __restrict__ whh,
    const unsigned short* __restrict__ xp,
    unsigned short* __restrict__ hbuf,
    int* __restrict__ bar)
{
  const int wg = blockIdx.x;
  const int sg = wg & 15;
  const int rg = wg >> 4;
  const int tid = threadIdx.x;
  const int l = tid & 63;
  const int w = tid >> 6;
  const int lrow = l & 15;
  const int lk8 = (l >> 4) * 8;
  const int col = rg*64 + w*16 + lrow;          // hidden index this lane produces
  const int s_frag = sg*4 + (lrow & 3);         // sample for A-fragment (dup pad 4->16)
  int* cnt = bar + sg*64;                        // 256B-spaced per-group counter

  // Whh rows resident in registers: breg[kk] = Whh[col][kk*32 + lk8 .. +7]
  short8 breg[32];
  #pragma unroll
  for (int kk=0; kk<32; ++kk)
    breg[kk] = *(const short8*)&whh[(size_t)col*H_ + kk*32 + lk8];

  for (int t=0; t<T_; ++t) {
    f32x4 acc = {};
    if (t > 0) {
      const unsigned short* hp = (MODE==0)
        ? hbuf + ((size_t)s_frag*T_ + (t-1))*H_
        : hbuf + ((size_t)(((t-1)&1)*B_ + s_frag))*H_;
      short8 areg[32];
      #pragma unroll
      for (int kk=0; kk<32; ++kk)
        areg[kk] = *(const short8*)&hp[kk*32 + lk8];
      #pragma unroll
      for (int kk=0; kk<32; ++kk)
        acc = __builtin_amdgcn_mfma_f32_16x16x32_bf16(areg[kk], breg[kk], acc, 0,0,0);
    }
    // epilogue: D row = (l>>4)*4 + r; valid sample rows 0..3 live in lanes 0..15
    if (l < 16) {
      #pragma unroll
      for (int r=0; r<4; ++r) {
        const int s = sg*4 + r;
        float v = acc[r] + bf16_to_f32(xp[((size_t)s*T_ + t)*H_ + col]);
        v = fmaxf(v, 0.f);
        const unsigned short hv = f32_to_bf16(v);
        if (MODE==0) hbuf[((size_t)s*T_ + t)*H_ + col] = hv;
        else         hbuf[((size_t)((t&1)*B_ + s))*H_ + col] = hv;
      }
    }
    if (t < T_-1) group_barrier(cnt, 16*(t+1));
  }
}

// ---------- final FC: out[64,256] = h2 @ fcW^T + fcb (f32 out) ----------
__global__ __launch_bounds__(64) void fc_kernel(const unsigned short* __restrict__ h,
                                                const unsigned short* __restrict__ fw,
                                                const float* __restrict__ fb,
                                                float* __restrict__ out) {
  const int l = threadIdx.x;
  const int bx = blockIdx.x, by = blockIdx.y;   // bx: 16 col tiles, by: 4 row tiles
  const int lrow = l & 15, lk8 = (l>>4)*8;
  f32x4 acc = {};
  #pragma unroll
  for (int kk=0; kk<32; ++kk) {
    short8 a = *(const short8*)&h [(size_t)(by*16 + lrow)*H_ + kk*32 + lk8];
    short8 b = *(const short8*)&fw[(size_t)(bx*16 + lrow)*H_ + kk*32 + lk8];
    acc = __builtin_amdgcn_mfma_f32_16x16x32_bf16(a, b, acc, 0,0,0);
  }
  const int col = bx*16 + lrow;
  const float bv = fb[col];
  #pragma unroll
  for (int r=0;r<4;++r) {
    const int row = by*16 + (l>>4)*4 + r;
    out[row*O_ + col] = acc[r] + bv;
  }
}

// ---------- launch ----------
extern "C" void kernel_launch(void* const* d_in, const int* in_sizes, int n_in,
                              void* d_out, int out_size, void* d_ws, size_t ws_size,
                              hipStream_t stream) {
  const float* x    = (const float*)d_in[0];
  const float* wih0 = (const float*)d_in[1];
  const float* bih0 = (const float*)d_in[2];
  const float* whh0 = (const float*)d_in[3];
  const float* bhh0 = (const float*)d_in[4];
  const float* wih1 = (const float*)d_in[5];
  const float* bih1 = (const float*)d_in[6];
  const float* whh1 = (const float*)d_in[7];
  const float* bhh1 = (const float*)d_in[8];
  const float* fcw  = (const float*)d_in[9];
  const float* fcb  = (const float*)d_in[10];

  char* ws = (char*)d_ws;
  // workspace layout (bytes). total ~151.3 MiB
  unsigned short* XBF  = (unsigned short*)(ws + 0);          // 16,777,216  x bf16
  unsigned short* WIH0 = (unsigned short*)(ws + 16777216);   //    524,288
  unsigned short* WHH0 = (unsigned short*)(ws + 17301504);   //  2,097,152
  unsigned short* WIH1 = (unsigned short*)(ws + 19398656);   //  2,097,152
  unsigned short* WHH1 = (unsigned short*)(ws + 21495808);   //  2,097,152
  unsigned short* FCW  = (unsigned short*)(ws + 23592960);   //    524,288
  float*          BIAS0= (float*)(ws + 24117248);            //      4,096
  float*          BIAS1= (float*)(ws + 24121344);            //      4,096
  unsigned short* XP   = (unsigned short*)(ws + 24125440);   // 67,108,864  (xp0 then xp1)
  unsigned short* H1   = (unsigned short*)(ws + 91234304);   // 67,108,864
  unsigned short* H2   = (unsigned short*)(ws + 158343168);  //    262,144  ping-pong
  int*            BAR  = (int*)(ws + 158605312);             //      8,192  barrier counters

  // barrier counters must be zero each call (harness poisons ws once with 0xAA)
  hipMemsetAsync(BAR, 0, 8192, stream);

  // fp32 -> bf16 conversions
  cvt_f32_bf16<<<dim3(8192), 256, 0, stream>>>((const float4*)x,    (ushort4*)XBF,  2097152);
  cvt_f32_bf16<<<dim3(256),  256, 0, stream>>>((const float4*)wih0, (ushort4*)WIH0, 65536);
  cvt_f32_bf16<<<dim3(1024), 256, 0, stream>>>((const float4*)whh0, (ushort4*)WHH0, 262144);
  cvt_f32_bf16<<<dim3(1024), 256, 0, stream>>>((const float4*)wih1, (ushort4*)WIH1, 262144);
  cvt_f32_bf16<<<dim3(1024), 256, 0, stream>>>((const float4*)whh1, (ushort4*)WHH1, 262144);
  cvt_f32_bf16<<<dim3(256),  256, 0, stream>>>((const float4*)fcw,  (ushort4*)FCW,  65536);
  bias_sum<<<dim3(4), 256, 0, stream>>>(bih0, bhh0, BIAS0, H_);
  bias_sum<<<dim3(4), 256, 0, stream>>>(bih1, bhh1, BIAS1, H_);

  // xp0 = x @ Wih0^T + (bih0+bhh0)   [M=32768, N=1024, K=256]
  gemm_bt<0><<<dim3(8, 256), 256, 0, stream>>>(XBF, WIH0, BIAS0, XP, H_, I_);
  // scan layer 0 -> H1[B*T][H]
  rnn_scan<0><<<256, 256, 0, stream>>>(WHH0, XP, H1, BAR);
  // xp1 = H1 @ Wih1^T + (bih1+bhh1)  [M=32768, N=1024, K=1024]
  gemm_bt<0><<<dim3(8, 256), 256, 0, stream>>>(H1, WIH1, BIAS1, XP, H_, H_);
  // scan layer 1 -> ping-pong, final state in slot 1
  rnn_scan<1><<<256, 256, 0, stream>>>(WHH1, XP, H2, BAR + 1024);
  // out = h2_last @ fcW^T + fcb
  fc_kernel<<<dim3(16, 4), 64, 0, stream>>>(H2 + (size_t)B_*H_, FCW, fcb, (float*)d_out);
}

// Round 2
// 10806.632 us; speedup vs baseline: 3.1861x; 3.1861x over previous
//
#include <hip/hip_runtime.h>
#include <cstdint>
#include <cstddef>

// ---------- types ----------
typedef __attribute__((ext_vector_type(8))) short short8;   // 8 bf16 in 4 VGPRs
typedef __attribute__((ext_vector_type(4))) float f32x4;

#define B_ 64
#define T_ 512
#define I_ 256
#define H_ 1024
#define O_ 256

__device__ __forceinline__ unsigned short f32_to_bf16(float f) {
  unsigned int u = __float_as_uint(f);
  u += 0x7fffu + ((u >> 16) & 1u);           // RNE
  return (unsigned short)(u >> 16);
}
__device__ __forceinline__ float bf16_to_f32(unsigned short h) {
  return __uint_as_float(((unsigned int)h) << 16);
}

__device__ __forceinline__ void gload_lds16(const void* g, void* l) {
  __builtin_amdgcn_global_load_lds((const __attribute__((address_space(1))) void*)g,
                                   (__attribute__((address_space(3))) void*)l, 16, 0, 0);
}

// MALL-write-through 2B store (bypasses L1/L2 so no fence/flush is ever needed)
__device__ __forceinline__ void store_short_sc(void* p, unsigned short v) {
  unsigned int vv = v;
  asm volatile("global_store_short %0, %1, off sc0 sc1" :: "v"(p), "v"(vv) : "memory");
}
// MALL-coherent 8B load (compiler-managed deps -> safe scheduling into MFMA)
__device__ __forceinline__ unsigned long long load_u64_sc(const void* p) {
  return __hip_atomic_load((const unsigned long long*)p, __ATOMIC_RELAXED,
                           __HIP_MEMORY_SCOPE_AGENT);
}

// ---------- conversion kernels ----------
__global__ void cvt_f32_bf16(const float4* __restrict__ s, ushort4* __restrict__ d, int n4) {
  int i = blockIdx.x * blockDim.x + threadIdx.x;
  if (i >= n4) return;
  float4 v = s[i];
  ushort4 o;
  o.x = f32_to_bf16(v.x); o.y = f32_to_bf16(v.y);
  o.z = f32_to_bf16(v.z); o.w = f32_to_bf16(v.w);
  d[i] = o;
}

__global__ void bias_sum(const float* __restrict__ a, const float* __restrict__ b,
                         float* __restrict__ o, int n) {
  int i = blockIdx.x * blockDim.x + threadIdx.x;
  if (i < n) o[i] = a[i] + b[i];
}

// ---------- GEMM: C[M,N] = A[M,K] @ Bm[N,K]^T + bias, 128x128 tile (m97 structure) ----------
template<int OUT_F32>
__global__ __launch_bounds__(256) void gemm_bt(
    const unsigned short* __restrict__ A, const unsigned short* __restrict__ Bm,
    const float* __restrict__ bias, void* __restrict__ Cout, int N_, int K_)
{
  __shared__ unsigned short As[128*32];
  __shared__ unsigned short Bs[128*32];
  const int tid = threadIdx.x;
  const int l = tid & 63, w = tid >> 6;
  const int row0 = blockIdx.y * 128, col0 = blockIdx.x * 128;
  const int wr = w >> 1, wc = w & 1;          // 2x2 waves, each 64x64
  const int lrow = l & 15, lk8 = (l >> 4) * 8;

  f32x4 acc[4][4] = {};

  const int nkb = K_ >> 5;
  for (int kb = 0; kb < nkb; ++kb) {
    #pragma unroll
    for (int c = 0; c < 2; ++c) {
      const int off = w*2048 + c*1024 + l*16;   // byte offset within 8KB tile
      const int row = off >> 6, colb = off & 63;
      gload_lds16((const char*)A  + ((size_t)(row0+row)*K_ + kb*32)*2 + colb,
                  (char*)As + w*2048 + c*1024);
      gload_lds16((const char*)Bm + ((size_t)(col0+row)*K_ + kb*32)*2 + colb,
                  (char*)Bs + w*2048 + c*1024);
    }
    __syncthreads();
    short8 af[4], bfr[4];
    #pragma unroll
    for (int m=0;m<4;++m) af[m]  = *(const short8*)&As[(wr*64 + m*16 + lrow)*32 + lk8];
    #pragma unroll
    for (int n=0;n<4;++n) bfr[n] = *(const short8*)&Bs[(wc*64 + n*16 + lrow)*32 + lk8];
    #pragma unroll
    for (int m=0;m<4;++m)
      #pragma unroll
      for (int n=0;n<4;++n)
        acc[m][n] = __builtin_amdgcn_mfma_f32_16x16x32_bf16(af[m], bfr[n], acc[m][n], 0,0,0);
    __syncthreads();
  }

  #pragma unroll
  for (int n=0;n<4;++n) {
    const int col = col0 + wc*64 + n*16 + lrow;
    const float bv = bias[col];
    #pragma unroll
    for (int m=0;m<4;++m) {
      const int rowb = row0 + wr*64 + m*16 + (l>>4)*4;
      #pragma unroll
      for (int r=0;r<4;++r) {
        const float v = acc[m][n][r] + bv;
        if (OUT_F32) ((float*)Cout)[(size_t)(rowb+r)*N_ + col] = v;
        else ((unsigned short*)Cout)[(size_t)(rowb+r)*N_ + col] = f32_to_bf16(v);
      }
    }
  }
}

// ---------- group barrier (16 wgs per sample-group) ----------
// All data traffic goes through the MALL via sc0/sc1 ops, so this barrier needs
// NO cache maintenance: drain stores (release), relaxed add + relaxed poll,
// workgroup-acquire fence (waitcnt only) to pin compiler ordering.
__device__ __forceinline__ void group_barrier(int* cnt, int expected) {
  asm volatile("s_waitcnt vmcnt(0)" ::: "memory");   // h-stores have reached MALL
  __syncthreads();
  if (threadIdx.x == 0) {
    __hip_atomic_fetch_add(cnt, 1, __ATOMIC_RELAXED, __HIP_MEMORY_SCOPE_AGENT);
    while (__hip_atomic_load(cnt, __ATOMIC_RELAXED, __HIP_MEMORY_SCOPE_AGENT) < expected) {}
  }
  __syncthreads();
  __builtin_amdgcn_fence(__ATOMIC_ACQUIRE, "workgroup");  // no cache ops at this scope
}

// ---------- RNN scan ----------
// 256 wgs: sg = wg&15 (4 samples), rg = wg>>4 (64 hidden rows). 4 waves, wave w
// owns 16 rows (one N-tile), Whh rows held in registers across all 512 steps.
// h state is exchanged through the MALL (sc0/sc1 stores+loads), never cached.
// MODE 0: h buffer is H1[B*T][H] (reads t-1 row, writes t row).
// MODE 1: h buffer is ping-pong [2][B][H]; final state in slot (T-1)&1 = 1.
template<int MODE>
__global__ __launch_bounds__(256, 1) void rnn_scan(
    const unsigned short* __restrict__ whh,
    const unsigned short* __restrict__ xp,
    unsigned short* __restrict__ hbuf,
    int* __restrict__ bar)
{
  const int wg = blockIdx.x;
  const int sg = wg & 15;
  const int rg = wg >> 4;
  const int tid = threadIdx.x;
  const int l = tid & 63;
  const int w = tid >> 6;
  const int lrow = l & 15;
  const int lk8 = (l >> 4) * 8;
  const int col = rg*64 + w*16 + lrow;          // hidden index this lane produces
  const int s_frag = sg*4 + (lrow & 3);         // sample for A-fragment (dup pad 4->16)
  int* cnt = bar + sg*64;                        // 256B-spaced per-group counter

  // Whh rows resident in registers: breg[kk] = Whh[col][kk*32 + lk8 .. +7]
  short8 breg[32];
  #pragma unroll
  for (int kk=0; kk<32; ++kk)
    breg[kk] = *(const short8*)&whh[(size_t)col*H_ + kk*32 + lk8];

  for (int t=0; t<T_; ++t) {
    f32x4 acc = {};
    if (t > 0) {
      const unsigned short* hp = (MODE==0)
        ? hbuf + ((size_t)s_frag*T_ + (t-1))*H_
        : hbuf + ((size_t)(((t-1)&1)*B_ + s_frag))*H_;
      short8 areg[32];
      #pragma unroll
      for (int kk=0; kk<32; ++kk) {
        union { unsigned long long q[2]; short8 v; } u;
        u.q[0] = load_u64_sc(hp + kk*32 + lk8);
        u.q[1] = load_u64_sc(hp + kk*32 + lk8 + 4);
        areg[kk] = u.v;
      }
      #pragma unroll
      for (int kk=0; kk<32; ++kk)
        acc = __builtin_amdgcn_mfma_f32_16x16x32_bf16(areg[kk], breg[kk], acc, 0,0,0);
    }
    // epilogue: D row = (l>>4)*4 + r; valid sample rows 0..3 live in lanes 0..15
    if (l < 16) {
      #pragma unroll
      for (int r=0; r<4; ++r) {
        const int s = sg*4 + r;
        float v = acc[r] + bf16_to_f32(xp[((size_t)s*T_ + t)*H_ + col]);
        v = fmaxf(v, 0.f);
        const unsigned short hv = f32_to_bf16(v);
        unsigned short* dst = (MODE==0)
          ? hbuf + ((size_t)s*T_ + t)*H_ + col
          : hbuf + ((size_t)((t&1)*B_ + s))*H_ + col;
        store_short_sc(dst, hv);
      }
    }
    if (t < T_-1) group_barrier(cnt, 16*(t+1));
  }
}

// ---------- final FC: out[64,256] = h2 @ fcW^T + fcb (f32 out) ----------
__global__ __launch_bounds__(64) void fc_kernel(const unsigned short* __restrict__ h,
                                                const unsigned short* __restrict__ fw,
                                                const float* __restrict__ fb,
                                                float* __restrict__ out) {
  const int l = threadIdx.x;
  const int bx = blockIdx.x, by = blockIdx.y;   // bx: 16 col tiles, by: 4 row tiles
  const int lrow = l & 15, lk8 = (l>>4)*8;
  f32x4 acc = {};
  #pragma unroll
  for (int kk=0; kk<32; ++kk) {
    short8 a = *(const short8*)&h [(size_t)(by*16 + lrow)*H_ + kk*32 + lk8];
    short8 b = *(const short8*)&fw[(size_t)(bx*16 + lrow)*H_ + kk*32 + lk8];
    acc = __builtin_amdgcn_mfma_f32_16x16x32_bf16(a, b, acc, 0,0,0);
  }
  const int col = bx*16 + lrow;
  const float bv = fb[col];
  #pragma unroll
  for (int r=0;r<4;++r) {
    const int row = by*16 + (l>>4)*4 + r;
    out[row*O_ + col] = acc[r] + bv;
  }
}

// ---------- launch ----------
extern "C" void kernel_launch(void* const* d_in, const int* in_sizes, int n_in,
                              void* d_out, int out_size, void* d_ws, size_t ws_size,
                              hipStream_t stream) {
  const float* x    = (const float*)d_in[0];
  const float* wih0 = (const float*)d_in[1];
  const float* bih0 = (const float*)d_in[2];
  const float* whh0 = (const float*)d_in[3];
  const float* bhh0 = (const float*)d_in[4];
  const float* wih1 = (const float*)d_in[5];
  const float* bih1 = (const float*)d_in[6];
  const float* whh1 = (const float*)d_in[7];
  const float* bhh1 = (const float*)d_in[8];
  const float* fcw  = (const float*)d_in[9];
  const float* fcb  = (const float*)d_in[10];

  char* ws = (char*)d_ws;
  // workspace layout (bytes). total ~151.3 MiB
  unsigned short* XBF  = (unsigned short*)(ws + 0);          // 16,777,216  x bf16
  unsigned short* WIH0 = (unsigned short*)(ws + 16777216);   //    524,288
  unsigned short* WHH0 = (unsigned short*)(ws + 17301504);   //  2,097,152
  unsigned short* WIH1 = (unsigned short*)(ws + 19398656);   //  2,097,152
  unsigned short* WHH1 = (unsigned short*)(ws + 21495808);   //  2,097,152
  unsigned short* FCW  = (unsigned short*)(ws + 23592960);   //    524,288
  float*          BIAS0= (float*)(ws + 24117248);            //      4,096
  float*          BIAS1= (float*)(ws + 24121344);            //      4,096
  unsigned short* XP   = (unsigned short*)(ws + 24125440);   // 67,108,864  (xp0 then xp1)
  unsigned short* H1   = (unsigned short*)(ws + 91234304);   // 67,108,864
  unsigned short* H2   = (unsigned short*)(ws + 158343168);  //    262,144  ping-pong
  int*            BAR  = (int*)(ws + 158605312);             //      8,192  barrier counters

  // barrier counters must be zero each call (harness poisons ws once with 0xAA)
  hipMemsetAsync(BAR, 0, 8192, stream);

  // fp32 -> bf16 conversions
  cvt_f32_bf16<<<dim3(8192), 256, 0, stream>>>((const float4*)x,    (ushort4*)XBF,  2097152);
  cvt_f32_bf16<<<dim3(256),  256, 0, stream>>>((const float4*)wih0, (ushort4*)WIH0, 65536);
  cvt_f32_bf16<<<dim3(1024), 256, 0, stream>>>((const float4*)whh0, (ushort4*)WHH0, 262144);
  cvt_f32_bf16<<<dim3(1024), 256, 0, stream>>>((const float4*)wih1, (ushort4*)WIH1, 262144);
  cvt_f32_bf16<<<dim3(1024), 256, 0, stream>>>((const float4*)whh1, (ushort4*)WHH1, 262144);
  cvt_f32_bf16<<<dim3(256),  256, 0, stream>>>((const float4*)fcw,  (ushort4*)FCW,  65536);
  bias_sum<<<dim3(4), 256, 0, stream>>>(bih0, bhh0, BIAS0, H_);
  bias_sum<<<dim3(4), 256, 0, stream>>>(bih1, bhh1, BIAS1, H_);

  // xp0 = x @ Wih0^T + (bih0+bhh0)   [M=32768, N=1024, K=256]
  gemm_bt<0><<<dim3(8, 256), 256, 0, stream>>>(XBF, WIH0, BIAS0, XP, H_, I_);
  // scan layer 0 -> H1[B*T][H]
  rnn_scan<0><<<256, 256, 0, stream>>>(WHH0, XP, H1, BAR);
  // xp1 = H1 @ Wih1^T + (bih1+bhh1)  [M=32768, N=1024, K=1024]
  gemm_bt<0><<<dim3(8, 256), 256, 0, stream>>>(H1, WIH1, BIAS1, XP, H_, H_);
  // scan layer 1 -> ping-pong, final state in slot 1
  rnn_scan<1><<<256, 256, 0, stream>>>(WHH1, XP, H2, BAR + 1024);
  // out = h2_last @ fcW^T + fcb
  fc_kernel<<<dim3(16, 4), 64, 0, stream>>>(H2 + (size_t)B_*H_, FCW, fcb, (float*)d_out);
}

// Round 3
// 9671.610 us; speedup vs baseline: 3.5601x; 1.1174x over previous
//
#include <hip/hip_runtime.h>
#include <cstdint>
#include <cstddef>

// ---------- types ----------
typedef __attribute__((ext_vector_type(8))) short short8;   // 8 bf16 in 4 VGPRs
typedef __attribute__((ext_vector_type(4))) float f32x4;

#define B_ 64
#define T_ 512
#define I_ 256
#define H_ 1024
#define O_ 256

__device__ __forceinline__ unsigned short f32_to_bf16(float f) {
  unsigned int u = __float_as_uint(f);
  u += 0x7fffu + ((u >> 16) & 1u);           // RNE
  return (unsigned short)(u >> 16);
}
__device__ __forceinline__ float bf16_to_f32(unsigned short h) {
  return __uint_as_float(((unsigned int)h) << 16);
}

__device__ __forceinline__ void gload_lds16(const void* g, void* l) {
  __builtin_amdgcn_global_load_lds((const __attribute__((address_space(1))) void*)g,
                                   (__attribute__((address_space(3))) void*)l, 16, 0, 0);
}

// MALL-write-through 2B store (bypasses L1/L2 so no fence/flush is ever needed)
__device__ __forceinline__ void store_short_sc(void* p, unsigned short v) {
  unsigned int vv = v;
  asm volatile("global_store_short %0, %1, off sc0 sc1" :: "v"(p), "v"(vv) : "memory");
}
// MALL-coherent 8B load (compiler-managed deps -> safe scheduling into MFMA)
__device__ __forceinline__ unsigned long long load_u64_sc(const void* p) {
  return __hip_atomic_load((const unsigned long long*)p, __ATOMIC_RELAXED,
                           __HIP_MEMORY_SCOPE_AGENT);
}
// pinned (non-rematerializable) 16B load: executes exactly once, result lives in VGPRs
__device__ __forceinline__ short8 pinned_load16(const void* p) {
  short8 r;
  asm volatile("global_load_dwordx4 %0, %1, off" : "=v"(r) : "v"(p));
  return r;
}

// ---------- conversion kernels ----------
__global__ void cvt_f32_bf16(const float4* __restrict__ s, ushort4* __restrict__ d, int n4) {
  int i = blockIdx.x * blockDim.x + threadIdx.x;
  if (i >= n4) return;
  float4 v = s[i];
  ushort4 o;
  o.x = f32_to_bf16(v.x); o.y = f32_to_bf16(v.y);
  o.z = f32_to_bf16(v.z); o.w = f32_to_bf16(v.w);
  d[i] = o;
}

__global__ void bias_sum(const float* __restrict__ a, const float* __restrict__ b,
                         float* __restrict__ o, int n) {
  int i = blockIdx.x * blockDim.x + threadIdx.x;
  if (i < n) o[i] = a[i] + b[i];
}

// ---------- GEMM: C[M,N] = A[M,K] @ Bm[N,K]^T + bias, 128x128 tile (m97 structure) ----------
template<int OUT_F32>
__global__ __launch_bounds__(256) void gemm_bt(
    const unsigned short* __restrict__ A, const unsigned short* __restrict__ Bm,
    const float* __restrict__ bias, void* __restrict__ Cout, int N_, int K_)
{
  __shared__ unsigned short As[128*32];
  __shared__ unsigned short Bs[128*32];
  const int tid = threadIdx.x;
  const int l = tid & 63, w = tid >> 6;
  const int row0 = blockIdx.y * 128, col0 = blockIdx.x * 128;
  const int wr = w >> 1, wc = w & 1;          // 2x2 waves, each 64x64
  const int lrow = l & 15, lk8 = (l >> 4) * 8;

  f32x4 acc[4][4] = {};

  const int nkb = K_ >> 5;
  for (int kb = 0; kb < nkb; ++kb) {
    #pragma unroll
    for (int c = 0; c < 2; ++c) {
      const int off = w*2048 + c*1024 + l*16;   // byte offset within 8KB tile
      const int row = off >> 6, colb = off & 63;
      gload_lds16((const char*)A  + ((size_t)(row0+row)*K_ + kb*32)*2 + colb,
                  (char*)As + w*2048 + c*1024);
      gload_lds16((const char*)Bm + ((size_t)(col0+row)*K_ + kb*32)*2 + colb,
                  (char*)Bs + w*2048 + c*1024);
    }
    __syncthreads();
    short8 af[4], bfr[4];
    #pragma unroll
    for (int m=0;m<4;++m) af[m]  = *(const short8*)&As[(wr*64 + m*16 + lrow)*32 + lk8];
    #pragma unroll
    for (int n=0;n<4;++n) bfr[n] = *(const short8*)&Bs[(wc*64 + n*16 + lrow)*32 + lk8];
    #pragma unroll
    for (int m=0;m<4;++m)
      #pragma unroll
      for (int n=0;n<4;++n)
        acc[m][n] = __builtin_amdgcn_mfma_f32_16x16x32_bf16(af[m], bfr[n], acc[m][n], 0,0,0);
    __syncthreads();
  }

  #pragma unroll
  for (int n=0;n<4;++n) {
    const int col = col0 + wc*64 + n*16 + lrow;
    const float bv = bias[col];
    #pragma unroll
    for (int m=0;m<4;++m) {
      const int rowb = row0 + wr*64 + m*16 + (l>>4)*4;
      #pragma unroll
      for (int r=0;r<4;++r) {
        const float v = acc[m][n][r] + bv;
        if (OUT_F32) ((float*)Cout)[(size_t)(rowb+r)*N_ + col] = v;
        else ((unsigned short*)Cout)[(size_t)(rowb+r)*N_ + col] = f32_to_bf16(v);
      }
    }
  }
}

// ---------- group barrier (16 wgs per sample-group) ----------
// All data traffic goes through the MALL via sc0/sc1 ops, so this barrier needs
// NO cache maintenance: drain stores (release), relaxed add + relaxed poll,
// workgroup-acquire fence (waitcnt only) to pin compiler ordering.
__device__ __forceinline__ void group_barrier(int* cnt, int expected) {
  asm volatile("s_waitcnt vmcnt(0)" ::: "memory");   // h-stores have reached MALL
  __syncthreads();
  if (threadIdx.x == 0) {
    __hip_atomic_fetch_add(cnt, 1, __ATOMIC_RELAXED, __HIP_MEMORY_SCOPE_AGENT);
    while (__hip_atomic_load(cnt, __ATOMIC_RELAXED, __HIP_MEMORY_SCOPE_AGENT) < expected) {}
  }
  __syncthreads();
  __builtin_amdgcn_fence(__ATOMIC_ACQUIRE, "workgroup");  // no cache ops at this scope
}

// ---------- RNN scan ----------
// 256 wgs: sg = wg&15 (4 samples), rg = wg>>4 (64 hidden rows). 4 waves, wave w
// owns 16 rows (one N-tile), Whh rows PINNED in VGPRs (inline-asm loads) for
// all 512 steps. h state is exchanged through the MALL (sc0/sc1), never cached.
// xp for step t+1 is prefetched across the barrier (completed by its vmcnt(0)).
// MODE 0: h buffer is H1[B*T][H] (reads t-1 row, writes t row).
// MODE 1: h buffer is ping-pong [2][B][H]; final state in slot (T-1)&1 = 1.
template<int MODE>
__global__ __launch_bounds__(256, 1) void rnn_scan(
    const unsigned short* __restrict__ whh,
    const unsigned short* __restrict__ xp,
    unsigned short* __restrict__ hbuf,
    int* __restrict__ bar)
{
  const int wg = blockIdx.x;
  const int sg = wg & 15;
  const int rg = wg >> 4;
  const int tid = threadIdx.x;
  const int l = tid & 63;
  const int w = tid >> 6;
  const int lrow = l & 15;
  const int lk8 = (l >> 4) * 8;
  const int col = rg*64 + w*16 + lrow;          // hidden index this lane produces
  const int s_frag = sg*4 + (lrow & 3);         // sample for A-fragment (dup pad 4->16)
  int* cnt = bar + sg*64;                        // 256B-spaced per-group counter

  // Whh rows pinned in registers: breg[kk] = Whh[col][kk*32 + lk8 .. +7]
  // asm volatile => executed once, results MUST stay in VGPRs (no remat/sink).
  short8 breg[32];
  #pragma unroll
  for (int kk=0; kk<32; ++kk)
    breg[kk] = pinned_load16(&whh[(size_t)col*H_ + kk*32 + lk8]);
  asm volatile("s_waitcnt vmcnt(0)" ::: "memory");
  __builtin_amdgcn_sched_barrier(0);

  // prefetch xp for t=0 (all lanes load; only l<16 consumes)
  unsigned short xc[4], xn[4];
  #pragma unroll
  for (int r=0; r<4; ++r)
    xc[r] = xp[((size_t)(sg*4+r)*T_ + 0)*H_ + col];

  for (int t=0; t<T_; ++t) {
    f32x4 acc = {};
    if (t > 0) {
      const unsigned short* hp = (MODE==0)
        ? hbuf + ((size_t)s_frag*T_ + (t-1))*H_
        : hbuf + ((size_t)(((t-1)&1)*B_ + s_frag))*H_;
      short8 areg[32];
      #pragma unroll
      for (int kk=0; kk<32; ++kk) {
        union { unsigned long long q[2]; short8 v; } u;
        u.q[0] = load_u64_sc(hp + kk*32 + lk8);
        u.q[1] = load_u64_sc(hp + kk*32 + lk8 + 4);
        areg[kk] = u.v;
      }
      #pragma unroll
      for (int kk=0; kk<32; ++kk)
        acc = __builtin_amdgcn_mfma_f32_16x16x32_bf16(areg[kk], breg[kk], acc, 0,0,0);
    }
    // epilogue: D row = (l>>4)*4 + r; valid sample rows 0..3 live in lanes 0..15
    if (l < 16) {
      #pragma unroll
      for (int r=0; r<4; ++r) {
        const int s = sg*4 + r;
        float v = acc[r] + bf16_to_f32(xc[r]);
        v = fmaxf(v, 0.f);
        const unsigned short hv = f32_to_bf16(v);
        unsigned short* dst = (MODE==0)
          ? hbuf + ((size_t)s*T_ + t)*H_ + col
          : hbuf + ((size_t)((t&1)*B_ + s))*H_ + col;
        store_short_sc(dst, hv);
      }
    }
    // prefetch xp[t+1]: issued before the barrier, completed by its vmcnt(0)
    const int tn = (t+1 < T_) ? (t+1) : t;
    #pragma unroll
    for (int r=0; r<4; ++r)
      xn[r] = xp[((size_t)(sg*4+r)*T_ + tn)*H_ + col];
    if (t < T_-1) group_barrier(cnt, 16*(t+1));
    #pragma unroll
    for (int r=0; r<4; ++r) xc[r] = xn[r];
  }
}

// ---------- final FC: out[64,256] = h2 @ fcW^T + fcb (f32 out) ----------
__global__ __launch_bounds__(64) void fc_kernel(const unsigned short* __restrict__ h,
                                                const unsigned short* __restrict__ fw,
                                                const float* __restrict__ fb,
                                                float* __restrict__ out) {
  const int l = threadIdx.x;
  const int bx = blockIdx.x, by = blockIdx.y;   // bx: 16 col tiles, by: 4 row tiles
  const int lrow = l & 15, lk8 = (l>>4)*8;
  f32x4 acc = {};
  #pragma unroll
  for (int kk=0; kk<32; ++kk) {
    short8 a = *(const short8*)&h [(size_t)(by*16 + lrow)*H_ + kk*32 + lk8];
    short8 b = *(const short8*)&fw[(size_t)(bx*16 + lrow)*H_ + kk*32 + lk8];
    acc = __builtin_amdgcn_mfma_f32_16x16x32_bf16(a, b, acc, 0,0,0);
  }
  const int col = bx*16 + lrow;
  const float bv = fb[col];
  #pragma unroll
  for (int r=0;r<4;++r) {
    const int row = by*16 + (l>>4)*4 + r;
    out[row*O_ + col] = acc[r] + bv;
  }
}

// ---------- launch ----------
extern "C" void kernel_launch(void* const* d_in, const int* in_sizes, int n_in,
                              void* d_out, int out_size, void* d_ws, size_t ws_size,
                              hipStream_t stream) {
  const float* x    = (const float*)d_in[0];
  const float* wih0 = (const float*)d_in[1];
  const float* bih0 = (const float*)d_in[2];
  const float* whh0 = (const float*)d_in[3];
  const float* bhh0 = (const float*)d_in[4];
  const float* wih1 = (const float*)d_in[5];
  const float* bih1 = (const float*)d_in[6];
  const float* whh1 = (const float*)d_in[7];
  const float* bhh1 = (const float*)d_in[8];
  const float* fcw  = (const float*)d_in[9];
  const float* fcb  = (const float*)d_in[10];

  char* ws = (char*)d_ws;
  // workspace layout (bytes). total ~151.3 MiB
  unsigned short* XBF  = (unsigned short*)(ws + 0);          // 16,777,216  x bf16
  unsigned short* WIH0 = (unsigned short*)(ws + 16777216);   //    524,288
  unsigned short* WHH0 = (unsigned short*)(ws + 17301504);   //  2,097,152
  unsigned short* WIH1 = (unsigned short*)(ws + 19398656);   //  2,097,152
  unsigned short* WHH1 = (unsigned short*)(ws + 21495808);   //  2,097,152
  unsigned short* FCW  = (unsigned short*)(ws + 23592960);   //    524,288
  float*          BIAS0= (float*)(ws + 24117248);            //      4,096
  float*          BIAS1= (float*)(ws + 24121344);            //      4,096
  unsigned short* XP   = (unsigned short*)(ws + 24125440);   // 67,108,864  (xp0 then xp1)
  unsigned short* H1   = (unsigned short*)(ws + 91234304);   // 67,108,864
  unsigned short* H2   = (unsigned short*)(ws + 158343168);  //    262,144  ping-pong
  int*            BAR  = (int*)(ws + 158605312);             //      8,192  barrier counters

  // barrier counters must be zero each call (harness poisons ws once with 0xAA)
  hipMemsetAsync(BAR, 0, 8192, stream);

  // fp32 -> bf16 conversions
  cvt_f32_bf16<<<dim3(8192), 256, 0, stream>>>((const float4*)x,    (ushort4*)XBF,  2097152);
  cvt_f32_bf16<<<dim3(256),  256, 0, stream>>>((const float4*)wih0, (ushort4*)WIH0, 65536);
  cvt_f32_bf16<<<dim3(1024), 256, 0, stream>>>((const float4*)whh0, (ushort4*)WHH0, 262144);
  cvt_f32_bf16<<<dim3(1024), 256, 0, stream>>>((const float4*)wih1, (ushort4*)WIH1, 262144);
  cvt_f32_bf16<<<dim3(1024), 256, 0, stream>>>((const float4*)whh1, (ushort4*)WHH1, 262144);
  cvt_f32_bf16<<<dim3(256),  256, 0, stream>>>((const float4*)fcw,  (ushort4*)FCW,  65536);
  bias_sum<<<dim3(4), 256, 0, stream>>>(bih0, bhh0, BIAS0, H_);
  bias_sum<<<dim3(4), 256, 0, stream>>>(bih1, bhh1, BIAS1, H_);

  // xp0 = x @ Wih0^T + (bih0+bhh0)   [M=32768, N=1024, K=256]
  gemm_bt<0><<<dim3(8, 256), 256, 0, stream>>>(XBF, WIH0, BIAS0, XP, H_, I_);
  // scan layer 0 -> H1[B*T][H]
  rnn_scan<0><<<256, 256, 0, stream>>>(WHH0, XP, H1, BAR);
  // xp1 = H1 @ Wih1^T + (bih1+bhh1)  [M=32768, N=1024, K=1024]
  gemm_bt<0><<<dim3(8, 256), 256, 0, stream>>>(H1, WIH1, BIAS1, XP, H_, H_);
  // scan layer 1 -> ping-pong, final state in slot 1
  rnn_scan<1><<<256, 256, 0, stream>>>(WHH1, XP, H2, BAR + 1024);
  // out = h2_last @ fcW^T + fcb
  fc_kernel<<<dim3(16, 4), 64, 0, stream>>>(H2 + (size_t)B_*H_, FCW, fcb, (float*)d_out);
}

// Round 4
// 3374.787 us; speedup vs baseline: 10.2026x; 2.8658x over previous
//
#include <hip/hip_runtime.h>
#include <cstdint>
#include <cstddef>

// ---------- types ----------
typedef __attribute__((ext_vector_type(8))) short short8;   // 8 bf16 in 4 VGPRs
typedef __attribute__((ext_vector_type(4))) float f32x4;

#define B_ 64
#define T_ 512
#define I_ 256
#define H_ 1024
#define O_ 256

__device__ __forceinline__ unsigned short f32_to_bf16(float f) {
  unsigned int u = __float_as_uint(f);
  u += 0x7fffu + ((u >> 16) & 1u);           // RNE
  return (unsigned short)(u >> 16);
}
__device__ __forceinline__ float bf16_to_f32(unsigned short h) {
  return __uint_as_float(((unsigned int)h) << 16);
}

__device__ __forceinline__ void gload_lds16(const void* g, void* l) {
  __builtin_amdgcn_global_load_lds((const __attribute__((address_space(1))) void*)g,
                                   (__attribute__((address_space(3))) void*)l, 16, 0, 0);
}

// MALL-write-through 2B store (bypasses L1/L2 so no fence/flush is ever needed)
__device__ __forceinline__ void store_short_sc(void* p, unsigned short v) {
  unsigned int vv = v;
  asm volatile("global_store_short %0, %1, off sc0 sc1" :: "v"(p), "v"(vv) : "memory");
}
// MALL-coherent 16B load (inline asm: caller MUST s_waitcnt vmcnt before use!)
__device__ __forceinline__ short8 load16_sc(const void* p) {
  short8 r;
  asm volatile("global_load_dwordx4 %0, %1, off sc0 sc1" : "=v"(r) : "v"(p) : "memory");
  return r;
}
// pinned (non-rematerializable) 16B load: executes exactly once (cached path ok)
__device__ __forceinline__ short8 pinned_load16(const void* p) {
  short8 r;
  asm volatile("global_load_dwordx4 %0, %1, off" : "=v"(r) : "v"(p));
  return r;
}

// ---------- conversion kernels ----------
__global__ void cvt_f32_bf16(const float4* __restrict__ s, ushort4* __restrict__ d, int n4) {
  int i = blockIdx.x * blockDim.x + threadIdx.x;
  if (i >= n4) return;
  float4 v = s[i];
  ushort4 o;
  o.x = f32_to_bf16(v.x); o.y = f32_to_bf16(v.y);
  o.z = f32_to_bf16(v.z); o.w = f32_to_bf16(v.w);
  d[i] = o;
}

__global__ void bias_sum(const float* __restrict__ a, const float* __restrict__ b,
                         float* __restrict__ o, int n) {
  int i = blockIdx.x * blockDim.x + threadIdx.x;
  if (i < n) o[i] = a[i] + b[i];
}

// ---------- GEMM: C[M,N] = A[M,K] @ Bm[N,K]^T + bias, 128x128 tile (m97 structure) ----------
template<int OUT_F32>
__global__ __launch_bounds__(256) void gemm_bt(
    const unsigned short* __restrict__ A, const unsigned short* __restrict__ Bm,
    const float* __restrict__ bias, void* __restrict__ Cout, int N_, int K_)
{
  __shared__ unsigned short As[128*32];
  __shared__ unsigned short Bs[128*32];
  const int tid = threadIdx.x;
  const int l = tid & 63, w = tid >> 6;
  const int row0 = blockIdx.y * 128, col0 = blockIdx.x * 128;
  const int wr = w >> 1, wc = w & 1;          // 2x2 waves, each 64x64
  const int lrow = l & 15, lk8 = (l >> 4) * 8;

  f32x4 acc[4][4] = {};

  const int nkb = K_ >> 5;
  for (int kb = 0; kb < nkb; ++kb) {
    #pragma unroll
    for (int c = 0; c < 2; ++c) {
      const int off = w*2048 + c*1024 + l*16;   // byte offset within 8KB tile
      const int row = off >> 6, colb = off & 63;
      gload_lds16((const char*)A  + ((size_t)(row0+row)*K_ + kb*32)*2 + colb,
                  (char*)As + w*2048 + c*1024);
      gload_lds16((const char*)Bm + ((size_t)(col0+row)*K_ + kb*32)*2 + colb,
                  (char*)Bs + w*2048 + c*1024);
    }
    __syncthreads();
    short8 af[4], bfr[4];
    #pragma unroll
    for (int m=0;m<4;++m) af[m]  = *(const short8*)&As[(wr*64 + m*16 + lrow)*32 + lk8];
    #pragma unroll
    for (int n=0;n<4;++n) bfr[n] = *(const short8*)&Bs[(wc*64 + n*16 + lrow)*32 + lk8];
    #pragma unroll
    for (int m=0;m<4;++m)
      #pragma unroll
      for (int n=0;n<4;++n)
        acc[m][n] = __builtin_amdgcn_mfma_f32_16x16x32_bf16(af[m], bfr[n], acc[m][n], 0,0,0);
    __syncthreads();
  }

  #pragma unroll
  for (int n=0;n<4;++n) {
    const int col = col0 + wc*64 + n*16 + lrow;
    const float bv = bias[col];
    #pragma unroll
    for (int m=0;m<4;++m) {
      const int rowb = row0 + wr*64 + m*16 + (l>>4)*4;
      #pragma unroll
      for (int r=0;r<4;++r) {
        const float v = acc[m][n][r] + bv;
        if (OUT_F32) ((float*)Cout)[(size_t)(rowb+r)*N_ + col] = v;
        else ((unsigned short*)Cout)[(size_t)(rowb+r)*N_ + col] = f32_to_bf16(v);
      }
    }
  }
}

// ---------- RNN scan ----------
// 256 wgs: sg = wg&15 (4 samples), rg = wg>>4 (64 hidden rows). 4 waves, wave w
// owns 16 rows (one N-tile), Whh rows pinned in VGPRs for all 512 steps.
// h exchange per step: coalesced sc0/sc1 dwordx4 loads (wave w stages sample
// sg*4+w, 2KB) -> LDS -> fragment ds_reads. ~33k MALL requests/step device-wide
// (vs 262k for the scattered per-lane dwordx2 pattern).
// MODE 0: h buffer is H1[B*T][H]. MODE 1: ping-pong [2][B][H], final in slot 1.
template<int MODE>
__global__ __launch_bounds__(256, 1) void rnn_scan(
    const unsigned short* __restrict__ whh,
    const unsigned short* __restrict__ xp,
    unsigned short* __restrict__ hbuf,
    int* __restrict__ bar)
{
  // +16 element pad per row: row stride 2080B -> bank shift 8/row -> max 2-way (free)
  __shared__ unsigned short lds_h[4][1040];

  const int wg = blockIdx.x;
  const int sg = wg & 15;
  const int rg = wg >> 4;
  const int tid = threadIdx.x;
  const int l = tid & 63;
  const int w = tid >> 6;
  const int lrow = l & 15;
  const int lk8 = (l >> 4) * 8;
  const int col = rg*64 + w*16 + lrow;          // hidden index this lane produces
  const int arow = lrow & 3;                    // LDS A-row (4 samples dup to 16)
  int* cnt = bar + sg*64;                        // 256B-spaced per-group counter

  // Whh rows pinned in registers: breg[kk] = Whh[col][kk*32 + lk8 .. +7]
  short8 breg[32];
  #pragma unroll
  for (int kk=0; kk<32; ++kk)
    breg[kk] = pinned_load16(&whh[(size_t)col*H_ + kk*32 + lk8]);
  asm volatile("s_waitcnt vmcnt(0)" ::: "memory");
  __builtin_amdgcn_sched_barrier(0);

  // prefetch xp for t=0
  unsigned short xc[4], xn[4];
  #pragma unroll
  for (int r=0; r<4; ++r)
    xc[r] = xp[((size_t)(sg*4+r)*T_ + 0)*H_ + col];

  for (int t=0; t<T_; ++t) {
    f32x4 acc0 = {}, acc1 = {};
    if (t > 0) {
      // fragments from LDS; even/odd accumulators halve the dependent chain
      #pragma unroll
      for (int kk=0; kk<32; kk+=2) {
        short8 a0 = *(const short8*)&lds_h[arow][kk*32 + lk8];
        short8 a1 = *(const short8*)&lds_h[arow][(kk+1)*32 + lk8];
        acc0 = __builtin_amdgcn_mfma_f32_16x16x32_bf16(a0, breg[kk],   acc0, 0,0,0);
        acc1 = __builtin_amdgcn_mfma_f32_16x16x32_bf16(a1, breg[kk+1], acc1, 0,0,0);
      }
    }
    // epilogue: D row = (l>>4)*4 + r; valid sample rows 0..3 live in lanes 0..15
    if (l < 16) {
      #pragma unroll
      for (int r=0; r<4; ++r) {
        const int s = sg*4 + r;
        float v = acc0[r] + acc1[r] + bf16_to_f32(xc[r]);
        v = fmaxf(v, 0.f);
        const unsigned short hv = f32_to_bf16(v);
        unsigned short* dst = (MODE==0)
          ? hbuf + ((size_t)s*T_ + t)*H_ + col
          : hbuf + ((size_t)((t&1)*B_ + s))*H_ + col;
        store_short_sc(dst, hv);
      }
    }
    // prefetch xp[t+1] (cached path; drained by the barrier's vmcnt(0))
    const int tn = (t+1 < T_) ? (t+1) : t;
    #pragma unroll
    for (int r=0; r<4; ++r)
      xn[r] = xp[((size_t)(sg*4+r)*T_ + tn)*H_ + col];

    if (t < T_-1) {
      // ---- barrier + stage h_t into LDS for step t+1 ----
      asm volatile("s_waitcnt vmcnt(0)" ::: "memory");  // h-stores at MALL
      __syncthreads();                                   // all 4 waves drained; LDS reads of step t done
      if (tid == 0)
        __hip_atomic_fetch_add(cnt, 1, __ATOMIC_RELAXED, __HIP_MEMORY_SCOPE_AGENT);
      const int want = 16*(t+1);
      while (__hip_atomic_load(cnt, __ATOMIC_RELAXED, __HIP_MEMORY_SCOPE_AGENT) < want) {}
      // wave w stages sample sg*4+w (2KB contiguous, coalesced sc loads)
      const unsigned short* hrow = (MODE==0)
        ? hbuf + ((size_t)(sg*4+w)*T_ + t)*H_
        : hbuf + ((size_t)((t&1)*B_ + sg*4+w))*H_;
      short8 s0 = load16_sc(hrow + l*8);
      short8 s1 = load16_sc(hrow + 512 + l*8);
      asm volatile("s_waitcnt vmcnt(0)" ::: "memory");  // loads complete before ds_write
      *(short8*)&lds_h[w][l*8]       = s0;
      *(short8*)&lds_h[w][512 + l*8] = s1;
      __syncthreads();                                   // LDS visible to all waves
    }
    #pragma unroll
    for (int r=0; r<4; ++r) xc[r] = xn[r];
  }
}

// ---------- final FC: out[64,256] = h2 @ fcW^T + fcb (f32 out) ----------
__global__ __launch_bounds__(64) void fc_kernel(const unsigned short* __restrict__ h,
                                                const unsigned short* __restrict__ fw,
                                                const float* __restrict__ fb,
                                                float* __restrict__ out) {
  const int l = threadIdx.x;
  const int bx = blockIdx.x, by = blockIdx.y;   // bx: 16 col tiles, by: 4 row tiles
  const int lrow = l & 15, lk8 = (l>>4)*8;
  f32x4 acc = {};
  #pragma unroll
  for (int kk=0; kk<32; ++kk) {
    short8 a = *(const short8*)&h [(size_t)(by*16 + lrow)*H_ + kk*32 + lk8];
    short8 b = *(const short8*)&fw[(size_t)(bx*16 + lrow)*H_ + kk*32 + lk8];
    acc = __builtin_amdgcn_mfma_f32_16x16x32_bf16(a, b, acc, 0,0,0);
  }
  const int col = bx*16 + lrow;
  const float bv = fb[col];
  #pragma unroll
  for (int r=0;r<4;++r) {
    const int row = by*16 + (l>>4)*4 + r;
    out[row*O_ + col] = acc[r] + bv;
  }
}

// ---------- launch ----------
extern "C" void kernel_launch(void* const* d_in, const int* in_sizes, int n_in,
                              void* d_out, int out_size, void* d_ws, size_t ws_size,
                              hipStream_t stream) {
  const float* x    = (const float*)d_in[0];
  const float* wih0 = (const float*)d_in[1];
  const float* bih0 = (const float*)d_in[2];
  const float* whh0 = (const float*)d_in[3];
  const float* bhh0 = (const float*)d_in[4];
  const float* wih1 = (const float*)d_in[5];
  const float* bih1 = (const float*)d_in[6];
  const float* whh1 = (const float*)d_in[7];
  const float* bhh1 = (const float*)d_in[8];
  const float* fcw  = (const float*)d_in[9];
  const float* fcb  = (const float*)d_in[10];

  char* ws = (char*)d_ws;
  // workspace layout (bytes). total ~151.3 MiB
  unsigned short* XBF  = (unsigned short*)(ws + 0);          // 16,777,216  x bf16
  unsigned short* WIH0 = (unsigned short*)(ws + 16777216);   //    524,288
  unsigned short* WHH0 = (unsigned short*)(ws + 17301504);   //  2,097,152
  unsigned short* WIH1 = (unsigned short*)(ws + 19398656);   //  2,097,152
  unsigned short* WHH1 = (unsigned short*)(ws + 21495808);   //  2,097,152
  unsigned short* FCW  = (unsigned short*)(ws + 23592960);   //    524,288
  float*          BIAS0= (float*)(ws + 24117248);            //      4,096
  float*          BIAS1= (float*)(ws + 24121344);            //      4,096
  unsigned short* XP   = (unsigned short*)(ws + 24125440);   // 67,108,864  (xp0 then xp1)
  unsigned short* H1   = (unsigned short*)(ws + 91234304);   // 67,108,864
  unsigned short* H2   = (unsigned short*)(ws + 158343168);  //    262,144  ping-pong
  int*            BAR  = (int*)(ws + 158605312);             //      8,192  barrier counters

  // barrier counters must be zero each call (harness poisons ws once with 0xAA)
  hipMemsetAsync(BAR, 0, 8192, stream);

  // fp32 -> bf16 conversions
  cvt_f32_bf16<<<dim3(8192), 256, 0, stream>>>((const float4*)x,    (ushort4*)XBF,  2097152);
  cvt_f32_bf16<<<dim3(256),  256, 0, stream>>>((const float4*)wih0, (ushort4*)WIH0, 65536);
  cvt_f32_bf16<<<dim3(1024), 256, 0, stream>>>((const float4*)whh0, (ushort4*)WHH0, 262144);
  cvt_f32_bf16<<<dim3(1024), 256, 0, stream>>>((const float4*)wih1, (ushort4*)WIH1, 262144);
  cvt_f32_bf16<<<dim3(1024), 256, 0, stream>>>((const float4*)whh1, (ushort4*)WHH1, 262144);
  cvt_f32_bf16<<<dim3(256),  256, 0, stream>>>((const float4*)fcw,  (ushort4*)FCW,  65536);
  bias_sum<<<dim3(4), 256, 0, stream>>>(bih0, bhh0, BIAS0, H_);
  bias_sum<<<dim3(4), 256, 0, stream>>>(bih1, bhh1, BIAS1, H_);

  // xp0 = x @ Wih0^T + (bih0+bhh0)   [M=32768, N=1024, K=256]
  gemm_bt<0><<<dim3(8, 256), 256, 0, stream>>>(XBF, WIH0, BIAS0, XP, H_, I_);
  // scan layer 0 -> H1[B*T][H]
  rnn_scan<0><<<256, 256, 0, stream>>>(WHH0, XP, H1, BAR);
  // xp1 = H1 @ Wih1^T + (bih1+bhh1)  [M=32768, N=1024, K=1024]
  gemm_bt<0><<<dim3(8, 256), 256, 0, stream>>>(H1, WIH1, BIAS1, XP, H_, H_);
  // scan layer 1 -> ping-pong, final state in slot 1
  rnn_scan<1><<<256, 256, 0, stream>>>(WHH1, XP, H2, BAR + 1024);
  // out = h2_last @ fcW^T + fcb
  fc_kernel<<<dim3(16, 4), 64, 0, stream>>>(H2 + (size_t)B_*H_, FCW, fcb, (float*)d_out);
}

// Round 5
// 2532.470 us; speedup vs baseline: 13.5960x; 1.3326x over previous
//
#include <hip/hip_runtime.h>
#include <cstdint>
#include <cstddef>

// ---------- types ----------
typedef __attribute__((ext_vector_type(8))) short short8;   // 8 bf16 in 4 VGPRs
typedef __attribute__((ext_vector_type(4))) float f32x4;

#define B_ 64
#define T_ 512
#define I_ 256
#define H_ 1024
#define O_ 256

__device__ __forceinline__ unsigned short f32_to_bf16(float f) {
  unsigned int u = __float_as_uint(f);
  u += 0x7fffu + ((u >> 16) & 1u);           // RNE
  return (unsigned short)(u >> 16);
}
__device__ __forceinline__ float bf16_to_f32(unsigned short h) {
  return __uint_as_float(((unsigned int)h) << 16);
}

__device__ __forceinline__ void gload_lds16(const void* g, void* l) {
  __builtin_amdgcn_global_load_lds((const __attribute__((address_space(1))) void*)g,
                                   (__attribute__((address_space(3))) void*)l, 16, 0, 0);
}

// MALL-write-through stores (bypass L1/L2 -> no cache maintenance ever needed)
__device__ __forceinline__ void store_short_sc(void* p, unsigned short v) {
  unsigned int vv = v;
  asm volatile("global_store_short %0, %1, off sc0 sc1" :: "v"(p), "v"(vv) : "memory");
}
__device__ __forceinline__ void store_int_sc(void* p, int v) {
  asm volatile("global_store_dword %0, %1, off sc0 sc1" :: "v"(p), "v"(v) : "memory");
}
// MALL-coherent 16B load (inline asm: caller MUST s_waitcnt vmcnt before use!)
__device__ __forceinline__ short8 load16_sc(const void* p) {
  short8 r;
  asm volatile("global_load_dwordx4 %0, %1, off sc0 sc1" : "=v"(r) : "v"(p) : "memory");
  return r;
}
// pinned (non-rematerializable) 16B load: executes exactly once (cached path ok)
__device__ __forceinline__ short8 pinned_load16(const void* p) {
  short8 r;
  asm volatile("global_load_dwordx4 %0, %1, off" : "=v"(r) : "v"(p));
  return r;
}

// ---------- conversion kernels ----------
__global__ void cvt_f32_bf16(const float4* __restrict__ s, ushort4* __restrict__ d, int n4) {
  int i = blockIdx.x * blockDim.x + threadIdx.x;
  if (i >= n4) return;
  float4 v = s[i];
  ushort4 o;
  o.x = f32_to_bf16(v.x); o.y = f32_to_bf16(v.y);
  o.z = f32_to_bf16(v.z); o.w = f32_to_bf16(v.w);
  d[i] = o;
}

__global__ void bias_sum(const float* __restrict__ a, const float* __restrict__ b,
                         float* __restrict__ o, int n) {
  int i = blockIdx.x * blockDim.x + threadIdx.x;
  if (i < n) o[i] = a[i] + b[i];
}

// ---------- GEMM: C[M,N] = A[M,K] @ Bm[N,K]^T + bias, 128x128 tile (m97 structure) ----------
template<int OUT_F32>
__global__ __launch_bounds__(256) void gemm_bt(
    const unsigned short* __restrict__ A, const unsigned short* __restrict__ Bm,
    const float* __restrict__ bias, void* __restrict__ Cout, int N_, int K_)
{
  __shared__ unsigned short As[128*32];
  __shared__ unsigned short Bs[128*32];
  const int tid = threadIdx.x;
  const int l = tid & 63, w = tid >> 6;
  const int row0 = blockIdx.y * 128, col0 = blockIdx.x * 128;
  const int wr = w >> 1, wc = w & 1;          // 2x2 waves, each 64x64
  const int lrow = l & 15, lk8 = (l >> 4) * 8;

  f32x4 acc[4][4] = {};

  const int nkb = K_ >> 5;
  for (int kb = 0; kb < nkb; ++kb) {
    #pragma unroll
    for (int c = 0; c < 2; ++c) {
      const int off = w*2048 + c*1024 + l*16;   // byte offset within 8KB tile
      const int row = off >> 6, colb = off & 63;
      gload_lds16((const char*)A  + ((size_t)(row0+row)*K_ + kb*32)*2 + colb,
                  (char*)As + w*2048 + c*1024);
      gload_lds16((const char*)Bm + ((size_t)(col0+row)*K_ + kb*32)*2 + colb,
                  (char*)Bs + w*2048 + c*1024);
    }
    __syncthreads();
    short8 af[4], bfr[4];
    #pragma unroll
    for (int m=0;m<4;++m) af[m]  = *(const short8*)&As[(wr*64 + m*16 + lrow)*32 + lk8];
    #pragma unroll
    for (int n=0;n<4;++n) bfr[n] = *(const short8*)&Bs[(wc*64 + n*16 + lrow)*32 + lk8];
    #pragma unroll
    for (int m=0;m<4;++m)
      #pragma unroll
      for (int n=0;n<4;++n)
        acc[m][n] = __builtin_amdgcn_mfma_f32_16x16x32_bf16(af[m], bfr[n], acc[m][n], 0,0,0);
    __syncthreads();
  }

  #pragma unroll
  for (int n=0;n<4;++n) {
    const int col = col0 + wc*64 + n*16 + lrow;
    const float bv = bias[col];
    #pragma unroll
    for (int m=0;m<4;++m) {
      const int rowb = row0 + wr*64 + m*16 + (l>>4)*4;
      #pragma unroll
      for (int r=0;r<4;++r) {
        const float v = acc[m][n][r] + bv;
        if (OUT_F32) ((float*)Cout)[(size_t)(rowb+r)*N_ + col] = v;
        else ((unsigned short*)Cout)[(size_t)(rowb+r)*N_ + col] = f32_to_bf16(v);
      }
    }
  }
}

// ---------- RNN scan ----------
// 128 wgs x 512 threads: sg = wg&15 (4 samples), rgO = wg>>4 (128 cols via 8
// waves x 16 cols). Whh rows pinned in AGPR/VGPR for all 512 steps. Exchange:
// sc stores -> per-wg flag dword (monotone step counter, 8-flag line per group)
// -> coalesced sc loads -> LDS. xp prefetched 2 steps ahead via asm ushort
// loads with counted vmcnt so they never sit in a critical drain.
// MODE 0: h buffer is H1[B*T][H]. MODE 1: ping-pong [2][B][H], final in slot 1.
#define SCAN_STEP(tcur, XREG)                                                        \
  {                                                                                  \
    const int t = (tcur);                                                            \
    f32x4 acc0 = {}, acc1 = {}, acc2 = {}, acc3 = {};                                \
    if (t > 0) {                                                                     \
      _Pragma("unroll")                                                              \
      for (int kk = 0; kk < 32; kk += 4) {                                           \
        short8 a0 = *(const short8*)&lds_h[arow][(kk+0)*32 + lk8];                   \
        short8 a1 = *(const short8*)&lds_h[arow][(kk+1)*32 + lk8];                   \
        short8 a2 = *(const short8*)&lds_h[arow][(kk+2)*32 + lk8];                   \
        short8 a3 = *(const short8*)&lds_h[arow][(kk+3)*32 + lk8];                   \
        acc0 = __builtin_amdgcn_mfma_f32_16x16x32_bf16(a0, breg[kk+0], acc0, 0,0,0); \
        acc1 = __builtin_amdgcn_mfma_f32_16x16x32_bf16(a1, breg[kk+1], acc1, 0,0,0); \
        acc2 = __builtin_amdgcn_mfma_f32_16x16x32_bf16(a2, breg[kk+2], acc2, 0,0,0); \
        acc3 = __builtin_amdgcn_mfma_f32_16x16x32_bf16(a3, breg[kk+3], acc3, 0,0,0); \
      }                                                                              \
    }                                                                                \
    if (l < 16) {                                                                    \
      _Pragma("unroll")                                                              \
      for (int r = 0; r < 4; ++r) {                                                  \
        const int s = sg*4 + r;                                                      \
        float v = acc0[r] + acc1[r] + acc2[r] + acc3[r]                              \
                + bf16_to_f32((unsigned short)XREG[r]);                              \
        v = fmaxf(v, 0.f);                                                           \
        const unsigned short hv = f32_to_bf16(v);                                    \
        unsigned short* dst = (MODE==0)                                              \
          ? hbuf + ((size_t)s*T_ + t)*H_ + col                                       \
          : hbuf + ((size_t)((t&1)*B_ + s))*H_ + col;                                \
        store_short_sc(dst, hv);                                                     \
      }                                                                              \
    }                                                                                \
    if (t < T_-1) {                                                                  \
      asm volatile("s_waitcnt vmcnt(0)" ::: "memory");   /* h-stores at MALL */      \
      __syncthreads();                                   /* all 8 waves drained */   \
      if (tid == 0) store_int_sc(&flags[rgO], t+1);                                  \
      { int fv;                                                                      \
        do { fv = __hip_atomic_load(flags + (l & 7), __ATOMIC_RELAXED,               \
                                    __HIP_MEMORY_SCOPE_AGENT);                       \
        } while (!__all(fv >= t+1)); }                                               \
      const unsigned short* hrow = (MODE==0)                                         \
        ? hbuf + ((size_t)(sg*4 + (w>>1))*T_ + t)*H_                                 \
        : hbuf + ((size_t)((t&1)*B_ + sg*4 + (w>>1)))*H_;                            \
      const int tn = (t+2 < T_) ? (t+2) : (T_-1);                                    \
      const unsigned short* xpp = xp + ((size_t)(sg*4)*T_ + tn)*H_ + col;            \
      short8 sv = load16_sc(hrow + (w&1)*512 + l*8);     /* 1 outstanding */         \
      _Pragma("unroll")                                                              \
      for (int r = 0; r < 4; ++r)                        /* +4 outstanding */        \
        asm volatile("global_load_ushort %0, %1, off"                               \
                     : "=v"(XREG[r]) : "v"(xpp + (size_t)r*T_*H_) : "memory");       \
      asm volatile("s_waitcnt vmcnt(4)" ::: "memory");   /* wait stage load only */  \
      *(short8*)&lds_h[w>>1][(w&1)*512 + l*8] = sv;                                  \
      __syncthreads();                                   /* LDS visible */           \
    }                                                                                \
  }

template<int MODE>
__global__ __launch_bounds__(512, 2) void rnn_scan(
    const unsigned short* __restrict__ whh,
    const unsigned short* __restrict__ xp,
    unsigned short* __restrict__ hbuf,
    int* __restrict__ bar)
{
  // +16 element pad per row: row stride 2080B -> 8-bank shift/row -> max 2-way (free)
  __shared__ unsigned short lds_h[4][1040];

  const int wg = blockIdx.x;          // 0..127
  const int sg = wg & 15;             // sample-group (4 samples)
  const int rgO = wg >> 4;            // 0..7 col-group (128 cols)
  const int tid = threadIdx.x;        // 0..511
  const int l = tid & 63;
  const int w = tid >> 6;             // 0..7
  const int lrow = l & 15;
  const int lk8 = (l >> 4) * 8;
  const int col = rgO*128 + w*16 + lrow;   // hidden index this lane produces
  const int arow = lrow & 3;               // LDS A-row (4 samples dup to 16)
  int* flags = bar + sg*16;                // 8 dwords used, 64B-spaced lines

  // Whh rows pinned in registers: breg[kk] = Whh[col][kk*32 + lk8 .. +7]
  short8 breg[32];
  #pragma unroll
  for (int kk=0; kk<32; ++kk)
    breg[kk] = pinned_load16(&whh[(size_t)col*H_ + kk*32 + lk8]);

  // xp pipeline: xa = xp[even t], xb = xp[odd t]; reloaded 2 steps ahead.
  unsigned int xa[4], xb[4];
  #pragma unroll
  for (int r=0; r<4; ++r) {
    asm volatile("global_load_ushort %0, %1, off" : "=v"(xa[r])
      : "v"(xp + ((size_t)(sg*4+r)*T_ + 0)*H_ + col) : "memory");
    asm volatile("global_load_ushort %0, %1, off" : "=v"(xb[r])
      : "v"(xp + ((size_t)(sg*4+r)*T_ + 1)*H_ + col) : "memory");
  }
  asm volatile("s_waitcnt vmcnt(0)" ::: "memory");
  __builtin_amdgcn_sched_barrier(0);

  for (int t2 = 0; t2 < T_; t2 += 2) {
    SCAN_STEP(t2,   xa);   // reloads xa = xp[t2+2]; completed by step t2+1's vmcnt(0)
    SCAN_STEP(t2+1, xb);   // reloads xb = xp[t2+3]
  }
}

// ---------- final FC: out[64,256] = h2 @ fcW^T + fcb (f32 out) ----------
__global__ __launch_bounds__(64) void fc_kernel(const unsigned short* __restrict__ h,
                                                const unsigned short* __restrict__ fw,
                                                const float* __restrict__ fb,
                                                float* __restrict__ out) {
  const int l = threadIdx.x;
  const int bx = blockIdx.x, by = blockIdx.y;   // bx: 16 col tiles, by: 4 row tiles
  const int lrow = l & 15, lk8 = (l>>4)*8;
  f32x4 acc = {};
  #pragma unroll
  for (int kk=0; kk<32; ++kk) {
    short8 a = *(const short8*)&h [(size_t)(by*16 + lrow)*H_ + kk*32 + lk8];
    short8 b = *(const short8*)&fw[(size_t)(bx*16 + lrow)*H_ + kk*32 + lk8];
    acc = __builtin_amdgcn_mfma_f32_16x16x32_bf16(a, b, acc, 0,0,0);
  }
  const int col = bx*16 + lrow;
  const float bv = fb[col];
  #pragma unroll
  for (int r=0;r<4;++r) {
    const int row = by*16 + (l>>4)*4 + r;
    out[row*O_ + col] = acc[r] + bv;
  }
}

// ---------- launch ----------
extern "C" void kernel_launch(void* const* d_in, const int* in_sizes, int n_in,
                              void* d_out, int out_size, void* d_ws, size_t ws_size,
                              hipStream_t stream) {
  const float* x    = (const float*)d_in[0];
  const float* wih0 = (const float*)d_in[1];
  const float* bih0 = (const float*)d_in[2];
  const float* whh0 = (const float*)d_in[3];
  const float* bhh0 = (const float*)d_in[4];
  const float* wih1 = (const float*)d_in[5];
  const float* bih1 = (const float*)d_in[6];
  const float* whh1 = (const float*)d_in[7];
  const float* bhh1 = (const float*)d_in[8];
  const float* fcw  = (const float*)d_in[9];
  const float* fcb  = (const float*)d_in[10];

  char* ws = (char*)d_ws;
  // workspace layout (bytes). total ~151.3 MiB
  unsigned short* XBF  = (unsigned short*)(ws + 0);          // 16,777,216  x bf16
  unsigned short* WIH0 = (unsigned short*)(ws + 16777216);   //    524,288
  unsigned short* WHH0 = (unsigned short*)(ws + 17301504);   //  2,097,152
  unsigned short* WIH1 = (unsigned short*)(ws + 19398656);   //  2,097,152
  unsigned short* WHH1 = (unsigned short*)(ws + 21495808);   //  2,097,152
  unsigned short* FCW  = (unsigned short*)(ws + 23592960);   //    524,288
  float*          BIAS0= (float*)(ws + 24117248);            //      4,096
  float*          BIAS1= (float*)(ws + 24121344);            //      4,096
  unsigned short* XP   = (unsigned short*)(ws + 24125440);   // 67,108,864  (xp0 then xp1)
  unsigned short* H1   = (unsigned short*)(ws + 91234304);   // 67,108,864
  unsigned short* H2   = (unsigned short*)(ws + 158343168);  //    262,144  ping-pong
  int*            BAR  = (int*)(ws + 158605312);             //      8,192  flag lines

  // flag lines must be zero each call (harness poisons ws once with 0xAA)
  hipMemsetAsync(BAR, 0, 8192, stream);

  // fp32 -> bf16 conversions
  cvt_f32_bf16<<<dim3(8192), 256, 0, stream>>>((const float4*)x,    (ushort4*)XBF,  2097152);
  cvt_f32_bf16<<<dim3(256),  256, 0, stream>>>((const float4*)wih0, (ushort4*)WIH0, 65536);
  cvt_f32_bf16<<<dim3(1024), 256, 0, stream>>>((const float4*)whh0, (ushort4*)WHH0, 262144);
  cvt_f32_bf16<<<dim3(1024), 256, 0, stream>>>((const float4*)wih1, (ushort4*)WIH1, 262144);
  cvt_f32_bf16<<<dim3(1024), 256, 0, stream>>>((const float4*)whh1, (ushort4*)WHH1, 262144);
  cvt_f32_bf16<<<dim3(256),  256, 0, stream>>>((const float4*)fcw,  (ushort4*)FCW,  65536);
  bias_sum<<<dim3(4), 256, 0, stream>>>(bih0, bhh0, BIAS0, H_);
  bias_sum<<<dim3(4), 256, 0, stream>>>(bih1, bhh1, BIAS1, H_);

  // xp0 = x @ Wih0^T + (bih0+bhh0)   [M=32768, N=1024, K=256]
  gemm_bt<0><<<dim3(8, 256), 256, 0, stream>>>(XBF, WIH0, BIAS0, XP, H_, I_);
  // scan layer 0 -> H1[B*T][H]
  rnn_scan<0><<<dim3(128), 512, 0, stream>>>(WHH0, XP, H1, BAR);
  // xp1 = H1 @ Wih1^T + (bih1+bhh1)  [M=32768, N=1024, K=1024]
  gemm_bt<0><<<dim3(8, 256), 256, 0, stream>>>(H1, WIH1, BIAS1, XP, H_, H_);
  // scan layer 1 -> ping-pong, final state in slot 1
  rnn_scan<1><<<dim3(128), 512, 0, stream>>>(WHH1, XP, H2, BAR + 1024);
  // out = h2_last @ fcW^T + fcb
  fc_kernel<<<dim3(16, 4), 64, 0, stream>>>(H2 + (size_t)B_*H_, FCW, fcb, (float*)d_out);
}